// Round 4
// baseline (759.113 us; speedup 1.0000x reference)
//
#include <hip/hip_runtime.h>
#include <hip/hip_bf16.h>

#define B_ 16384
#define E_ 1024
#define H_ 8
#define D_ 128

typedef _Float16 f16;
typedef _Float16 f16x8 __attribute__((ext_vector_type(8)));
typedef float f32x4 __attribute__((ext_vector_type(4)));

#define MFMA16(a, b, c) __builtin_amdgcn_mfma_f32_16x16x32_f16(a, b, c, 0, 0, 0)

// ---------------- X conversion: Xi16 = f16(image), Xd16 = f16(image - signal) ----------------
__global__ __launch_bounds__(256) void cvtX_kernel(
    const float4* __restrict__ im, const float4* __restrict__ sg,
    uint4* __restrict__ xi, uint4* __restrict__ xd, int n8)
{
    int i = blockIdx.x * 256 + threadIdx.x;
    if (i >= n8) return;
    float4 a0 = im[2 * i], a1 = im[2 * i + 1];
    float4 b0 = sg[2 * i], b1 = sg[2 * i + 1];
    union { uint4 u; f16 h[8]; } vi, vd;
    vi.h[0] = (f16)a0.x; vi.h[1] = (f16)a0.y; vi.h[2] = (f16)a0.z; vi.h[3] = (f16)a0.w;
    vi.h[4] = (f16)a1.x; vi.h[5] = (f16)a1.y; vi.h[6] = (f16)a1.z; vi.h[7] = (f16)a1.w;
    vd.h[0] = (f16)(a0.x - b0.x); vd.h[1] = (f16)(a0.y - b0.y);
    vd.h[2] = (f16)(a0.z - b0.z); vd.h[3] = (f16)(a0.w - b0.w);
    vd.h[4] = (f16)(a1.x - b1.x); vd.h[5] = (f16)(a1.y - b1.y);
    vd.h[6] = (f16)(a1.z - b1.z); vd.h[7] = (f16)(a1.w - b1.w);
    xi[i] = vi.u;
    xd[i] = vd.u;
}

// ---------------- W conversion: 4 weight matrices, blockIdx.y selects ----------------
__global__ __launch_bounds__(256) void cvtW_kernel(
    const float4* __restrict__ w0, const float4* __restrict__ w1,
    const float4* __restrict__ w2, const float4* __restrict__ w3,
    ushort4* __restrict__ d0, ushort4* __restrict__ d1,
    ushort4* __restrict__ d2, ushort4* __restrict__ d3, int n4)
{
    int i = blockIdx.x * 256 + threadIdx.x;
    if (i >= n4) return;
    const float4* s; ushort4* d;
    switch (blockIdx.y) {
        case 0: s = w0; d = d0; break;
        case 1: s = w1; d = d1; break;
        case 2: s = w2; d = d2; break;
        default: s = w3; d = d3; break;
    }
    float4 v = s[i];
    union { ushort4 u; f16 h[4]; } o;
    o.h[0] = (f16)v.x; o.h[1] = (f16)v.y; o.h[2] = (f16)v.z; o.h[3] = (f16)v.w;
    d[i] = o.u;
}

// ---------------- fused QKV + 2-key attention -> ctx (direct-to-register, no LDS in K-loop) ----
// delta = (Q+bq)·Kd ; Kd = Xd@Wk^T ; ctx = Vi - a1*Vd + bv ; a1 = 1/(1+exp(delta*scale))
// grid (H, B/64): blockIdx.x = head (consecutive blocks share X rows -> X fetched ~once).
// 256 thr = 4 waves, wave tile 64 rows x 32 cols per matrix; fragments loaded straight
// from global (16-row x 64B pattern per instruction). Zero K-loop barriers: loads of
// iter k+1 stay in flight during iter k's MFMAs; 8 waves/CU (2 blocks) add TLP.
__global__ __launch_bounds__(256, 2) void qkv_kernel(
    const f16* __restrict__ Xi, const f16* __restrict__ Xd,
    const f16* __restrict__ Wq, const f16* __restrict__ Wk, const f16* __restrict__ Wv,
    const float* __restrict__ bq, const float* __restrict__ bv,
    f16* __restrict__ ctx)
{
    __shared__ float sdot[64][4];
    __shared__ float sa1[64];

    const int tid  = threadIdx.x;
    const int lane = tid & 63;
    const int w    = tid >> 6;              // wave's 32-col slice: 0..3
    const int l16  = lane & 15, lq = lane >> 4;

    const int row0 = blockIdx.y * 64;
    const int colw = blockIdx.x * D_ + w * 32;

    // fragment base pointers (lane-resolved): frag m adds m*16 rows, frag n adds n*16 rows
    const f16* pI = Xi + (size_t)(row0 + l16) * E_ + lq * 8;
    const f16* pD = Xd + (size_t)(row0 + l16) * E_ + lq * 8;
    const f16* pQ = Wq + (size_t)(colw + l16) * E_ + lq * 8;
    const f16* pK = Wk + (size_t)(colw + l16) * E_ + lq * 8;
    const f16* pV = Wv + (size_t)(colw + l16) * E_ + lq * 8;

    f32x4 zero = {0.f, 0.f, 0.f, 0.f};
    f32x4 aQ[4][2], aK[4][2], aVi[4][2], aVd[4][2];
    #pragma unroll
    for (int m = 0; m < 4; m++)
        #pragma unroll
        for (int n = 0; n < 2; n++) { aQ[m][n] = zero; aK[m][n] = zero; aVi[m][n] = zero; aVd[m][n] = zero; }

    for (int kk = 0; kk < E_; kk += 32) {
        f16x8 fI[4], fDg[4], fQ[2], fK[2], fV[2];
        #pragma unroll
        for (int m = 0; m < 4; m++) {
            fI[m]  = *(const f16x8*)(pI + (size_t)m * 16 * E_ + kk);
            fDg[m] = *(const f16x8*)(pD + (size_t)m * 16 * E_ + kk);
        }
        #pragma unroll
        for (int n = 0; n < 2; n++) {
            fQ[n] = *(const f16x8*)(pQ + (size_t)n * 16 * E_ + kk);
            fK[n] = *(const f16x8*)(pK + (size_t)n * 16 * E_ + kk);
            fV[n] = *(const f16x8*)(pV + (size_t)n * 16 * E_ + kk);
        }
        #pragma unroll
        for (int m = 0; m < 4; m++)
            #pragma unroll
            for (int n = 0; n < 2; n++) {
                aQ[m][n]  = MFMA16(fI[m],  fQ[n], aQ[m][n]);
                aK[m][n]  = MFMA16(fDg[m], fK[n], aK[m][n]);
                aVi[m][n] = MFMA16(fI[m],  fV[n], aVi[m][n]);
                aVd[m][n] = MFMA16(fDg[m], fV[n], aVd[m][n]);
            }
    }

    // ---- delta = (Q+bq)·Kd per row (reduce 32 cols in-wave, 4 wave-slices via LDS) ----
    float bqv[2];
    #pragma unroll
    for (int n = 0; n < 2; n++) bqv[n] = bq[colw + n * 16 + l16];
    #pragma unroll
    for (int m = 0; m < 4; m++)
        #pragma unroll
        for (int e = 0; e < 4; e++) {
            float d = 0.f;
            #pragma unroll
            for (int n = 0; n < 2; n++)
                d += (aQ[m][n][e] + bqv[n]) * aK[m][n][e];
            d += __shfl_xor(d, 1, 64);
            d += __shfl_xor(d, 2, 64);
            d += __shfl_xor(d, 4, 64);
            d += __shfl_xor(d, 8, 64);
            if (l16 == 0) sdot[m * 16 + lq * 4 + e][w] = d;
        }
    __syncthreads();
    if (tid < 64) {
        const float scale = 0.088388347648318447f;  // 1/sqrt(128)
        float delta = (sdot[tid][0] + sdot[tid][1] + sdot[tid][2] + sdot[tid][3]) * scale;
        sa1[tid] = 1.0f / (1.0f + __expf(delta));
    }
    __syncthreads();

    // ---- ctx = Vi - a1*Vd + bv ----
    #pragma unroll
    for (int n = 0; n < 2; n++) {
        int col = colw + n * 16 + l16;
        float bvv = bv[col];
        #pragma unroll
        for (int m = 0; m < 4; m++)
            #pragma unroll
            for (int e = 0; e < 4; e++) {
                int row = m * 16 + lq * 4 + e;
                float a1r = sa1[row];
                ctx[(size_t)(row0 + row) * E_ + col] =
                    (f16)(aVi[m][n][e] - a1r * aVd[m][n][e] + bvv);
            }
    }
}

// ---------------- out projection: ctx @ Wo^T + bo + residual -> f32 ----------------
// grid (E/128, B/128): consecutive blocks share ctx rows. 256 thr, 4 waves 2x2,
// wave tile 64x64, direct-to-register fragment loads, NO barriers at all.
__global__ __launch_bounds__(256) void out_proj_kernel(
    const f16* __restrict__ A, const f16* __restrict__ Wo,
    const float* __restrict__ bo, const float* __restrict__ resid,
    float* __restrict__ out)
{
    const int tid  = threadIdx.x;
    const int lane = tid & 63;
    const int w    = tid >> 6;
    const int wr   = w >> 1, wc = w & 1;
    const int l16  = lane & 15, lq = lane >> 4;
    const int row0 = blockIdx.y * 128 + wr * 64;
    const int col0 = blockIdx.x * 128 + wc * 64;

    const f16* pA = A  + (size_t)(row0 + l16) * E_ + lq * 8;
    const f16* pB = Wo + (size_t)(col0 + l16) * E_ + lq * 8;

    f32x4 zero = {0.f, 0.f, 0.f, 0.f};
    f32x4 acc[4][4];
    #pragma unroll
    for (int i = 0; i < 4; i++)
        #pragma unroll
        for (int j = 0; j < 4; j++) acc[i][j] = zero;

    for (int kk = 0; kk < E_; kk += 32) {
        f16x8 fA[4], fB[4];
        #pragma unroll
        for (int f = 0; f < 4; f++) {
            fA[f] = *(const f16x8*)(pA + (size_t)f * 16 * E_ + kk);
            fB[f] = *(const f16x8*)(pB + (size_t)f * 16 * E_ + kk);
        }
        #pragma unroll
        for (int fr = 0; fr < 4; fr++)
            #pragma unroll
            for (int fc = 0; fc < 4; fc++)
                acc[fr][fc] = MFMA16(fA[fr], fB[fc], acc[fr][fc]);
    }

    #pragma unroll
    for (int fc = 0; fc < 4; fc++) {
        int col = col0 + fc * 16 + l16;
        float bov = bo[col];
        #pragma unroll
        for (int fr = 0; fr < 4; fr++)
            #pragma unroll
            for (int e = 0; e < 4; e++) {
                int row = row0 + fr * 16 + lq * 4 + e;
                out[(size_t)row * E_ + col] = acc[fr][fc][e] + bov + resid[(size_t)row * E_ + col];
            }
    }
}

// ---------------- in-place LayerNorm over E=1024 ----------------
__global__ __launch_bounds__(256) void ln_kernel(
    float* __restrict__ x, const float* __restrict__ gamma,
    const float* __restrict__ beta, float* __restrict__ out)
{
    const int row = blockIdx.x;
    const int tid = threadIdx.x;
    const float4* xr = (const float4*)(x + (size_t)row * E_);
    float4 v = xr[tid];
    float s  = v.x + v.y + v.z + v.w;
    float s2 = v.x * v.x + v.y * v.y + v.z * v.z + v.w * v.w;
    #pragma unroll
    for (int m = 1; m < 64; m <<= 1) {
        s  += __shfl_xor(s, m, 64);
        s2 += __shfl_xor(s2, m, 64);
    }
    __shared__ float red[8];
    int wv = tid >> 6, ln = tid & 63;
    if (ln == 0) { red[wv] = s; red[4 + wv] = s2; }
    __syncthreads();
    s  = red[0] + red[1] + red[2] + red[3];
    s2 = red[4] + red[5] + red[6] + red[7];
    float mu  = s * (1.0f / E_);
    float var = s2 * (1.0f / E_) - mu * mu;
    float r   = rsqrtf(var + 1e-5f);
    float4 g  = ((const float4*)gamma)[tid];
    float4 bb = ((const float4*)beta)[tid];
    float4 o;
    o.x = (v.x - mu) * r * g.x + bb.x;
    o.y = (v.y - mu) * r * g.y + bb.y;
    o.z = (v.z - mu) * r * g.z + bb.z;
    o.w = (v.w - mu) * r * g.w + bb.w;
    ((float4*)(out + (size_t)row * E_))[tid] = o;
}

extern "C" void kernel_launch(void* const* d_in, const int* in_sizes, int n_in,
                              void* d_out, int out_size, void* d_ws, size_t ws_size,
                              hipStream_t stream)
{
    (void)in_sizes; (void)n_in; (void)out_size; (void)ws_size;
    const float* image  = (const float*)d_in[0];
    const float* signal = (const float*)d_in[1];
    const float* Wq = (const float*)d_in[2];
    const float* Wk = (const float*)d_in[3];
    const float* Wv = (const float*)d_in[4];
    const float* bq = (const float*)d_in[5];
    const float* bv = (const float*)d_in[7];
    const float* Wo = (const float*)d_in[8];
    const float* bo = (const float*)d_in[9];
    const float* gamma = (const float*)d_in[10];
    const float* beta  = (const float*)d_in[11];
    float* out = (float*)d_out;

    char* ws = (char*)d_ws;
    f16* Xi16 = (f16*)(ws);                            // 32 MB
    f16* Xd16 = (f16*)(ws + 32ull * 1024 * 1024);      // 32 MB
    f16* Wq16 = (f16*)(ws + 64ull * 1024 * 1024);      // 2 MB
    f16* Wk16 = (f16*)(ws + 66ull * 1024 * 1024);      // 2 MB
    f16* Wv16 = (f16*)(ws + 68ull * 1024 * 1024);      // 2 MB
    f16* Wo16 = (f16*)(ws + 70ull * 1024 * 1024);      // 2 MB
    f16* ctx  = (f16*)(ws + 72ull * 1024 * 1024);      // 32 MB

    const int n8  = B_ * E_ / 8;    // 2097152
    const int n4w = E_ * E_ / 4;    // 262144
    cvtX_kernel<<<n8 / 256, 256, 0, stream>>>((const float4*)image, (const float4*)signal,
                                              (uint4*)Xi16, (uint4*)Xd16, n8);
    dim3 gw(n4w / 256, 4);
    cvtW_kernel<<<gw, 256, 0, stream>>>((const float4*)Wq, (const float4*)Wk,
                                        (const float4*)Wv, (const float4*)Wo,
                                        (ushort4*)Wq16, (ushort4*)Wk16,
                                        (ushort4*)Wv16, (ushort4*)Wo16, n4w);

    dim3 gq(H_, B_ / 64);          // x = head: row-sharing blocks are consecutive
    qkv_kernel<<<gq, 256, 0, stream>>>(Xi16, Xd16, Wq16, Wk16, Wv16, bq, bv, ctx);

    dim3 go(E_ / 128, B_ / 128);   // x = col-block: ctx-row-sharing blocks consecutive
    out_proj_kernel<<<go, 256, 0, stream>>>(ctx, Wo16, bo, image, out);

    ln_kernel<<<B_, 256, 0, stream>>>(out, gamma, beta, out);
}